// Round 2
// baseline (593.541 us; speedup 1.0000x reference)
//
#include <hip/hip_runtime.h>

// AFDChannelAttention on MI355X — fp32 in/out (x: [32,512,64,64] float32).
// rows BC=16384, L=4096, N_BASIS=64, R=0.9.
// proj = X*B^T via bf16 MFMA with hi/lo split of BOTH operands (3 chains,
// fp32-quality logits), softmax(|proj|), out = x + W*B (bf16 MFMA, fp32 add).

typedef short s16x8 __attribute__((ext_vector_type(8)));
typedef float f32x4 __attribute__((ext_vector_type(4)));

#define MFMA16(a, b, c) __builtin_amdgcn_mfma_f32_16x16x32_bf16((a), (b), (c), 0, 0, 0)

#define L_DIM   4096
#define N_BASIS 64
#define BC      16384

__device__ __forceinline__ float bf2f(ushort u) {
    union { unsigned int i; float f; } v; v.i = ((unsigned int)u) << 16; return v.f;
}
__device__ __forceinline__ ushort f2bf(float f) {
    union { float f; unsigned int i; } v; v.f = f;
    unsigned int i = v.i;
    return (ushort)((i + 0x7FFFu + ((i >> 16) & 1u)) >> 16);   // RNE
}

// ---------------------------------------------------------------------------
// Kernel 1: Blaschke basis, pre-swizzled into MFMA B-operand fragment layout.
//  b1h/b1l (GEMM1, K=l, col=n): elem (n,l) at ((l/8)*64+n)*8 + l%8
//  b2h     (GEMM2, K=n, col=l): elem (n,l) at ((n/8)*4096+l)*8 + n%8
// ---------------------------------------------------------------------------
__global__ __launch_bounds__(256) void afd_basis_kernel(ushort* __restrict__ b1h,
                                                        ushort* __restrict__ b1l,
                                                        ushort* __restrict__ b2h) {
    int idx = blockIdx.x * 256 + threadIdx.x;      // 0 .. 64*4096-1
    int n = idx & 63;
    int l = idx >> 6;
    // t_l = 2pi*l/4095 (endpoint=True), theta_n = 2pi*n/64 (endpoint=False)
    double ph = 6.283185307179586 * ((double)l / 4095.0 - (double)n / 64.0);
    float c = cosf((float)ph);
    float rc = 0.9f * c;
    float B = 0.435889894354f * (1.0f - rc) / (1.81f - 2.0f * rc);
    ushort hi = f2bf(B);
    float lo = B - bf2f(hi);
    ushort lo16 = f2bf(lo);
    int i1 = ((l >> 3) * 64 + n) * 8 + (l & 7);
    b1h[i1] = hi;
    b1l[i1] = lo16;
    int i2 = ((n >> 3) * 4096 + l) * 8 + (n & 7);
    b2h[i2] = hi;
}

// ---------------------------------------------------------------------------
// Kernel 2: fused proj -> softmax -> attn -> add, 16 rows per block.
// 256 threads = 4 waves; wave w owns n-tile w in GEMM1 and l-quarter w in GEMM2.
// ---------------------------------------------------------------------------
__global__ __launch_bounds__(256, 4) void afd_main_kernel(const float* __restrict__ x,
                                                          float* __restrict__ out,
                                                          const ushort* __restrict__ b1h,
                                                          const ushort* __restrict__ b1l,
                                                          const ushort* __restrict__ b2h) {
    __shared__ float  proj[16][68];
    __shared__ float  wtmp[16][64];
    __shared__ float  red[16][16];
    __shared__ float  rowstat[16];
    __shared__ ushort wbf[16][64];

    const int tid  = threadIdx.x;
    const int wave = tid >> 6;
    const int lane = tid & 63;
    const int l16  = lane & 15;
    const int q    = lane >> 4;
    const long rowbase = (long)blockIdx.x * 16;

    // ---------------- GEMM1: proj[16 rows][n-tile wave] -------------------
    // A-frag: lane holds x[rowbase+l16][k0 + q*8 .. +7], hi/lo split to bf16.
    // B-frag: pre-swizzled coalesced 16B/lane from L2-resident b1h/b1l.
    const float*  xp  = x + (rowbase + l16) * L_DIM + q * 8;
    const ushort* bhp = b1h + (wave * 16 + l16) * 8 + q * 512;
    const ushort* blp = b1l + (wave * 16 + l16) * 8 + q * 512;

    f32x4 acc_hh = {0.f, 0.f, 0.f, 0.f};
    f32x4 acc_hl = {0.f, 0.f, 0.f, 0.f};
    f32x4 acc_lh = {0.f, 0.f, 0.f, 0.f};
#pragma unroll 2
    for (int k0 = 0; k0 < L_DIM; k0 += 32) {
        f32x4 x0 = *(const f32x4*)(xp + k0);
        f32x4 x1 = *(const f32x4*)(xp + k0 + 4);
        s16x8 vh = *(const s16x8*)(bhp + (k0 << 6));   // k0*64 elems
        s16x8 vl = *(const s16x8*)(blp + (k0 << 6));
        s16x8 xh, xl;
#pragma unroll
        for (int j = 0; j < 4; ++j) {
            ushort h0 = f2bf(x0[j]);
            xh[j] = (short)h0;
            xl[j] = (short)f2bf(x0[j] - bf2f(h0));
            ushort h1 = f2bf(x1[j]);
            xh[4 + j] = (short)h1;
            xl[4 + j] = (short)f2bf(x1[j] - bf2f(h1));
        }
        acc_hh = MFMA16(xh, vh, acc_hh);
        acc_hl = MFMA16(xh, vl, acc_hl);
        acc_lh = MFMA16(xl, vh, acc_lh);
    }
    f32x4 p = acc_hh + (acc_hl + acc_lh);

    // C layout: col = lane&15 (= n within tile), row = q*4 + reg
#pragma unroll
    for (int r = 0; r < 4; ++r)
        proj[q * 4 + r][wave * 16 + l16] = p[r];
    __syncthreads();

    // ---------------- softmax(|proj|) over n=64, per row ------------------
    {
        const int row = tid >> 4;       // 16 rows
        const int i   = tid & 15;       // 16 segments of 4 n each
        float a0 = fabsf(proj[row][i * 4 + 0]);
        float a1 = fabsf(proj[row][i * 4 + 1]);
        float a2 = fabsf(proj[row][i * 4 + 2]);
        float a3 = fabsf(proj[row][i * 4 + 3]);
        red[row][i] = fmaxf(fmaxf(a0, a1), fmaxf(a2, a3));
        __syncthreads();
        if (tid < 16) {
            float rm = red[tid][0];
#pragma unroll
            for (int j = 1; j < 16; ++j) rm = fmaxf(rm, red[tid][j]);
            rowstat[tid] = rm;
        }
        __syncthreads();
        float rm = rowstat[row];
        float e0 = __expf(a0 - rm), e1 = __expf(a1 - rm);
        float e2 = __expf(a2 - rm), e3 = __expf(a3 - rm);
        wtmp[row][i * 4 + 0] = e0; wtmp[row][i * 4 + 1] = e1;
        wtmp[row][i * 4 + 2] = e2; wtmp[row][i * 4 + 3] = e3;
        red[row][i] = e0 + e1 + e2 + e3;
        __syncthreads();
        if (tid < 16) {
            float s = red[tid][0];
#pragma unroll
            for (int j = 1; j < 16; ++j) s += red[tid][j];
            rowstat[tid] = 1.0f / s;
        }
        __syncthreads();
        float inv = rowstat[row];
#pragma unroll
        for (int j = 0; j < 4; ++j)
            wbf[row][i * 4 + j] = f2bf(wtmp[row][i * 4 + j] * inv);
    }
    __syncthreads();

    // ---------------- GEMM2: out = x + W * B (fp32 epilogue) --------------
    s16x8 a0 = *(const s16x8*)&wbf[l16][q * 8];
    s16x8 a1 = *(const s16x8*)&wbf[l16][32 + q * 8];
    const f32x4 zero = {0.f, 0.f, 0.f, 0.f};

#pragma unroll 2
    for (int i = 0; i < 64; ++i) {
        const int l0 = (wave * 64 + i) * 16;
        s16x8 b0 = *(const s16x8*)(b2h + (q * 4096 + l0 + l16) * 8);
        s16x8 b1 = *(const s16x8*)(b2h + ((4 + q) * 4096 + l0 + l16) * 8);
        f32x4 c = MFMA16(a0, b0, zero);
        c = MFMA16(a1, b1, c);
        // C layout: col(l) = lane&15, row = q*4 + reg
        long base = (rowbase + q * 4) * (long)L_DIM + l0 + l16;
#pragma unroll
        for (int r = 0; r < 4; ++r) {
            long idx = base + (long)r * L_DIM;
            out[idx] = x[idx] + c[r];
        }
    }
}

// ---------------------------------------------------------------------------
extern "C" void kernel_launch(void* const* d_in, const int* in_sizes, int n_in,
                              void* d_out, int out_size, void* d_ws, size_t ws_size,
                              hipStream_t stream) {
    const float* x = (const float*)d_in[0];
    float* out = (float*)d_out;

    // workspace: 3 pre-swizzled basis arrays, 64*4096 bf16 each (512 KiB each)
    ushort* b1h = (ushort*)d_ws;
    ushort* b1l = b1h + (size_t)N_BASIS * L_DIM;
    ushort* b2h = b1l + (size_t)N_BASIS * L_DIM;

    // ws is re-poisoned before every launch -> rebuild basis every call
    afd_basis_kernel<<<(N_BASIS * L_DIM) / 256, 256, 0, stream>>>(b1h, b1l, b2h);
    afd_main_kernel<<<BC / 16, 256, 0, stream>>>(x, out, b1h, b1l, b2h);
}